// Round 9
// baseline (146.027 us; speedup 1.0000x reference)
//
#include <hip/hip_runtime.h>

#define D    160
#define D2   (D * D)
#define D3   (D * D * D)
#define NB   4
#define TX   8
#define TY   8
#define ZSL  20
#define HXL  3
#define WINX 15                          // x slots [xt-3 .. xt+11]
#define HYL  3
#define WINY 14                          // y slots [yt-3 .. yt+10]
#define HZL  4
#define ZWIN 28                          // z slots [zl-4 .. zl+23]
#define NROW (WINX * WINY)               // 210
#define LDSF (NROW * ZWIN)               // 5880 floats used
#define NSTAGE ((LDSF + 255) / 256)      // 23 global_load_lds per tile
#define LDSPAD (NSTAGE * 256)            // 5888 floats per buffer (23 KB)
#define TPB  640                         // 10 waves; 64 rows x 10 z-chunks(2)
#define NWAVE (TPB / 64)
#define TPDX (D / TX)                    // 20
#define TPDY (D / TY)                    // 20
#define NZS  (D / ZSL)                   // 8
#define NTILE (NB * TPDX * NZS * TPDY)   // 12800 tiles of 1280 voxels
#define NBLK 1280                        // 5 blocks/CU, 3 resident (46KB dbuf)
#define CNT  (NTILE / NBLK)              // 10 tiles per block, same (b,xi,zi)!
#define BASECLAMP (((WINX-2) * WINY + (WINY-2)) * ZWIN + (ZWIN-2))   // 5458

typedef float f32x2 __attribute__((ext_vector_type(2)));

struct StageCtx {
    int pfix[3];     // srcx*D2 + srcz (block-fixed)
    int syl[3];      // window y slot
    int ldof[3];     // LDS float offset
    bool have[3];    // wave-uniform validity
};

__device__ __forceinline__ void issue_stage(const float* __restrict__ vol,
                                            const StageCtx& sc, int yt, float* buf) {
#pragma unroll
    for (int i = 0; i < 3; ++i) {
        if (sc.have[i]) {            // wave-uniform branch
            int srcy = min(max(yt - HYL + sc.syl[i], 0), D - 1);
            const float* g = vol + sc.pfix[i] + srcy * D;
            __builtin_amdgcn_global_load_lds(
                (const __attribute__((address_space(1))) void*)g,
                (__attribute__((address_space(3))) void*)(buf + sc.ldof[i]),
                16, 0, 0);
        }
    }
}

__device__ __forceinline__ void do_iter(
    const float* __restrict__ vol, const float* __restrict__ ddf,
    float* __restrict__ out, const StageCtx& sc,
    int it, int yt, int vb,
    f32x2 q0, f32x2 q1, f32x2 q2,            // current tile's ddf (2 voxels)
    f32x2& n0, f32x2& n1, f32x2& n2,         // next tile's ddf (out)
    float* bufc, float* bufn,
    float xgf, int zg, int ry, int xwb, int zwb)
{
    const float maxf = (float)(D - 1);
    float ygf = (float)(yt + ry);
    const float dxs[2] = {q0.x, q1.y};
    const float dys[2] = {q0.y, q2.x};
    const float dzs[2] = {q1.x, q2.y};
    float wxs[2], wys[2], wzs[2];
    int bases[2];
    unsigned flags = 0, shb = 0;
    f32x2 fb00[2] = {}, fb01[2] = {}, fb10[2] = {}, fb11[2] = {};

    // ---- phase A: coords, weights, masked fallback loads (issued EARLY) ----
#pragma unroll
    for (int j = 0; j < 2; ++j) {
        float fx = xgf + dxs[j];
        float fy = ygf + dys[j];
        float fz = (float)(zg + j) + dzs[j];
        fx = fminf(fmaxf(fx, 0.0f), maxf);
        fy = fminf(fmaxf(fy, 0.0f), maxf);
        fz = fminf(fmaxf(fz, 0.0f), maxf);
        int x0 = (int)fx, y0 = (int)fy, z0 = (int)fz;
        wxs[j] = fx - (float)x0;
        wys[j] = fy - (float)y0;
        wzs[j] = fz - (float)z0;
        int sx0 = x0 - xwb, sy0 = y0 - (yt - HYL), sz0 = z0 - zwb;
        bool inWin = ((unsigned)sx0 <= (unsigned)(WINX - 2)) &
                     ((unsigned)sy0 <= (unsigned)(WINY - 2)) &
                     ((unsigned)sz0 <= (unsigned)(ZWIN - 2));
        flags |= (unsigned)inWin << j;
        int base = (sx0 * WINY + sy0) * ZWIN + sz0;
        // garbage-safe: when !inWin the value is overwritten; mask+min keeps the
        // address inside our LDS allocation (in-win max base = BASECLAMP)
        bases[j] = (int)min((unsigned)base & 8191u, (unsigned)BASECLAMP);
        if (!inWin) {                    // rare: |disp| beyond halo -> exact path
            int x1 = min(x0 + 1, D - 1);
            int y1 = min(y0 + 1, D - 1);
            int zc = min(z0, D - 2);
            shb |= (unsigned)(z0 > zc) << j;   // z0==159 -> wz==0
            fb00[j] = *(const f32x2*)(vol + x0 * D2 + y0 * D + zc);
            fb01[j] = *(const f32x2*)(vol + x0 * D2 + y1 * D + zc);
            fb10[j] = *(const f32x2*)(vol + x1 * D2 + y0 * D + zc);
            fb11[j] = *(const f32x2*)(vol + x1 * D2 + y1 * D + zc);
        }
    }

    // keep fb loads OLDER than the stage loads (in-order vmcnt retirement)
    __builtin_amdgcn_sched_barrier(0);

    // ---- issue next tile's ddf + stage into the other buffer ----
    if (it + 1 < CNT) {
        int vbn = vb + TY * D;
        const f32x2* dp = (const f32x2*)(ddf + (size_t)vbn * 3);
        n0 = __builtin_nontemporal_load(dp + 0);
        n1 = __builtin_nontemporal_load(dp + 1);
        n2 = __builtin_nontemporal_load(dp + 2);
        issue_stage(vol, sc, yt + TY, bufn);
    }
    __builtin_amdgcn_sched_barrier(0);

    // ---- phase B: LDS reads (select-free in z), interpolate, store ----
    float res[2];
#pragma unroll
    for (int j = 0; j < 2; ++j) {
        int b00 = bases[j];
        float a0 = bufc[b00],                     a1 = bufc[b00 + 1];
        float c0 = bufc[b00 + ZWIN],              c1 = bufc[b00 + ZWIN + 1];
        float e0 = bufc[b00 + WINY * ZWIN],       e1 = bufc[b00 + WINY * ZWIN + 1];
        float g0 = bufc[b00 + (WINY + 1) * ZWIN], g1 = bufc[b00 + (WINY + 1) * ZWIN + 1];
        if (!((flags >> j) & 1)) {
            bool sh = (shb >> j) & 1;
            a0 = sh ? fb00[j].y : fb00[j].x;  a1 = fb00[j].y;
            c0 = sh ? fb01[j].y : fb01[j].x;  c1 = fb01[j].y;
            e0 = sh ? fb10[j].y : fb10[j].x;  e1 = fb10[j].y;
            g0 = sh ? fb11[j].y : fb11[j].x;  g1 = fb11[j].y;
        }
        float wx = wxs[j], wy = wys[j], wz = wzs[j];
        float ux = 1.0f - wx, uy = 1.0f - wy, uz = 1.0f - wz;
        res[j] = (a0 * uz + a1 * wz) * (ux * uy)
               + (c0 * uz + c1 * wz) * (ux * wy)
               + (e0 * uz + e1 * wz) * (wx * uy)
               + (g0 * uz + g1 * wz) * (wx * wy);
    }
    f32x2 o = {res[0], res[1]};
    __builtin_nontemporal_store(o, (f32x2*)(out + vb));

    // counted wait: next stage + ddf done; only our out-store may stay in flight
    asm volatile("s_waitcnt vmcnt(1)" ::: "memory");
    __builtin_amdgcn_sched_barrier(0);
    __builtin_amdgcn_s_barrier();
    __builtin_amdgcn_sched_barrier(0);
}

__global__ __launch_bounds__(TPB) void warp_kernel(
    const float* __restrict__ ddf,     // [B, D, D, D, 3]
    const float* __restrict__ image,   // [B, D, D, D]
    float* __restrict__ out)           // [B, D, D, D]
{
    extern __shared__ float lds[];     // 2 * LDSPAD floats (46 KB) -> 3 WG/CU
    float* buf0 = lds;
    float* buf1 = lds + LDSPAD;

    // XCD-chunked mapping; a block's CNT tiles share (b, xi, zi) — only yt moves
    int g   = blockIdx.x;
    int gx8 = (g & 7) * (NBLK / 8) + (g >> 3);
    int yi0 = (gx8 & 1) * CNT;         // 0 or 10
    int bxz = gx8 >> 1;
    int zi  = bxz & (NZS - 1);
    int t2  = bxz >> 3;
    int xi  = t2 % TPDX;
    int b   = t2 / TPDX;

    const int tid  = threadIdx.x;
    const int w    = tid >> 6;
    const int lane = tid & 63;
    const int row  = tid / 10;             // 0..63
    const int zc   = tid - row * 10;       // 0..9
    const int zbl  = zc * 2;
    const int rx   = row >> 3, ry = row & 7;

    const int xg = xi * TX + rx;           // block-fixed
    const int zg = zi * ZSL + zbl;         // block-fixed
    const int xwb = xi * TX - HXL;
    const int zwb = zi * ZSL - HZL;
    const float xgf = (float)xg;
    const float* vol = image + (size_t)b * D3;

    // hoisted per-lane stage constants (x/z source fixed for the whole block)
    StageCtx sc;
#pragma unroll
    for (int i = 0; i < 3; ++i) {
        int k = w + i * NWAVE;
        sc.have[i] = (k < NSTAGE);
        int kk = sc.have[i] ? k : 0;
        int f  = kk * 256 + lane * 4;
        int s  = f / ZWIN;
        int zo = f - s * ZWIN;             // multiple of 4 -> 16B aligned
        int sx = s / WINY;
        int sy = s - sx * WINY;
        int srcx = min(max(xi * TX - HXL + sx, 0), D - 1);
        int srcz = min(max(zi * ZSL - HZL + zo, 0), D - 4);
        sc.pfix[i] = srcx * D2 + srcz;
        sc.syl[i]  = sy;
        sc.ldof[i] = kk * 256;
    }

    int yt = yi0 * TY;
    int vb = b * D3 + xg * D2 + (yt + ry) * D + zg;

    f32x2 qA0, qA1, qA2, qB0, qB1, qB2;

    // prologue: tile 0 ddf + stage, full drain once
    {
        const f32x2* dp = (const f32x2*)(ddf + (size_t)vb * 3);
        qA0 = __builtin_nontemporal_load(dp + 0);
        qA1 = __builtin_nontemporal_load(dp + 1);
        qA2 = __builtin_nontemporal_load(dp + 2);
        issue_stage(vol, sc, yt, buf0);
        asm volatile("s_waitcnt vmcnt(0)" ::: "memory");
        __builtin_amdgcn_sched_barrier(0);
        __builtin_amdgcn_s_barrier();
        __builtin_amdgcn_sched_barrier(0);
    }

#pragma unroll 1
    for (int it = 0; it < CNT; it += 2) {
        do_iter(vol, ddf, out, sc, it, yt, vb,
                qA0, qA1, qA2, qB0, qB1, qB2, buf0, buf1,
                xgf, zg, ry, xwb, zwb);
        yt += TY; vb += TY * D;
        do_iter(vol, ddf, out, sc, it + 1, yt, vb,
                qB0, qB1, qB2, qA0, qA1, qA2, buf1, buf0,
                xgf, zg, ry, xwb, zwb);
        yt += TY; vb += TY * D;
    }
}

extern "C" void kernel_launch(void* const* d_in, const int* in_sizes, int n_in,
                              void* d_out, int out_size, void* d_ws, size_t ws_size,
                              hipStream_t stream) {
    const float* ddf   = (const float*)d_in[0];
    const float* image = (const float*)d_in[1];
    float* out = (float*)d_out;

    warp_kernel<<<NBLK, TPB, 2 * LDSPAD * sizeof(float), stream>>>(ddf, image, out);
}

// Round 10
// 140.137 us; speedup vs baseline: 1.0420x; 1.0420x over previous
//
#include <hip/hip_runtime.h>

#define D    160
#define D2   (D * D)
#define D3   (D * D * D)
#define NB   4
#define TX   8
#define TY   8
#define ZSL  20
#define HXL  3
#define HYL  3
#define HZL  4
#define WINX 15                          // x slots [xt-3 .. xt+11]
#define WINY 14                          // y slots [yt-3 .. yt+10]
#define ZWIN 28                          // z slots [zl-4 .. zl+23]
#define LDSF (WINX * WINY * ZWIN)        // 5880 floats
#define NSTAGE 23                        // ceil(5880/256) global_load_lds per tile
#define LDSPAD (NSTAGE * 256)            // 5888 floats / buffer (23 KB); x3 = 69 KB
#define TPB  640
#define NWAVE 10
#define TPDX (D / TX)                    // 20
#define TPDY (D / TY)                    // 20
#define NZS  (D / ZSL)                   // 8
#define NGRP (NB * TPDX * NZS)           // 640 (b,xi,zi) groups
#define NTILE (NGRP * TPDY)              // 12800 tiles of 8x8x20 = 1280 voxels
#define NBLK 512                         // persistent: 2 blocks per CU
#define CNT  (NTILE / NBLK)              // 25 tiles per block (y-major order)
#define BASEMAX (((WINX-2) * WINY + (WINY-2)) * ZWIN + (ZWIN-2))   // 5458

typedef float f32x2 __attribute__((ext_vector_type(2)));

__global__ __launch_bounds__(TPB, 5) void warp_kernel(
    const float* __restrict__ ddf,     // [B, D, D, D, 3]
    const float* __restrict__ image,   // [B, D, D, D]
    float* __restrict__ out)           // [B, D, D, D]
{
    extern __shared__ float lds[];     // 3 * LDSPAD floats (69 KB) -> 2 WG/CU

    const int tid  = threadIdx.x;
    const int w    = tid >> 6;
    const int lane = tid & 63;
    const int row  = tid / 10;             // 0..63
    const int zch  = tid - row * 10;       // 0..9
    const int rx   = row >> 3, ry = row & 7, zbl = zch * 2;
    const int loff = rx * D2 + ry * D + zbl;

    // ---- stage lane constants (hoisted once) ----
    int s_sx[3], s_sy[3], s_zo[3];
    bool s_have[3];
#pragma unroll
    for (int i = 0; i < 3; ++i) {
        int k = w + i * NWAVE;
        s_have[i] = (k < NSTAGE);
        int kk = s_have[i] ? k : 0;
        int f = kk * 256 + lane * 4;       // multiple of 4 (28 = 4*7) -> 16B ok
        int s = f / ZWIN;
        s_zo[i] = f - s * ZWIN;
        s_sx[i] = s / WINY;
        s_sy[i] = s - s_sx[i] * WINY;
    }

    // ---- block -> first tile (XCD-chunked, bijective: 512 % 8 == 0) ----
    int g    = blockIdx.x;
    int gx8  = (g & 7) * (NBLK / 8) + (g >> 3);
    int sid0 = gx8 * CNT;
    int grp0 = sid0 / TPDY;
    int yi0  = sid0 - grp0 * TPDY;

    auto decodeGrp = [&](int grp, int& b, int& xi, int& zi) {
        zi = grp & (NZS - 1);
        int q = grp >> 3;
        xi = q % TPDX;
        b  = q / TPDX;
    };

    // ---- stage cursor ----
    int sg_grp, sg_yleft, sg_yt;
    int sg_pf[3], sg_pfy[3];
    auto sgInit = [&](int grp, int yi) {
        sg_grp = grp; sg_yleft = TPDY - yi; sg_yt = yi * TY;
        int b, xi, zi; decodeGrp(grp, b, xi, zi);
        int xwb = xi * TX - HXL, zwb = zi * ZSL - HZL, vol = b * D3;
#pragma unroll
        for (int i = 0; i < 3; ++i) {
            int srcx = min(max(xwb + s_sx[i], 0), D - 1);
            int srcz = min(max(zwb + s_zo[i], 0), D - 4);
            sg_pf[i]  = vol + srcx * D2 + srcz;
            sg_pfy[i] = sg_pf[i] + s_sy[i] * D;
        }
    };
    auto sgIssue = [&](float* buf) {
        if ((unsigned)(sg_yt - 8) <= 136u) {          // srcy never clamps
            const float* sbase = image + (sg_yt - HYL) * D;   // uniform addend
#pragma unroll
            for (int i = 0; i < 3; ++i) if (s_have[i]) {
                const float* gp = sbase + sg_pfy[i];
                __builtin_amdgcn_global_load_lds(
                    (const __attribute__((address_space(1))) void*)gp,
                    (__attribute__((address_space(3))) void*)(buf + (w + i*NWAVE)*256),
                    16, 0, 0);
            }
        } else {                                      // y-edge tiles: clamp
#pragma unroll
            for (int i = 0; i < 3; ++i) if (s_have[i]) {
                int srcy = min(max(sg_yt - HYL + s_sy[i], 0), D - 1);
                const float* gp = image + sg_pf[i] + srcy * D;
                __builtin_amdgcn_global_load_lds(
                    (const __attribute__((address_space(1))) void*)gp,
                    (__attribute__((address_space(3))) void*)(buf + (w + i*NWAVE)*256),
                    16, 0, 0);
            }
        }
    };
    auto sgAdv = [&]() {
        sg_yt += TY;
        if (--sg_yleft == 0) { sgInit(sg_grp + 1, 0); }
    };

    // ---- ddf cursor ----
    int df_grp, df_yleft, df_vb;
    auto dfInit = [&](int grp, int yi) {
        df_grp = grp; df_yleft = TPDY - yi;
        int b, xi, zi; decodeGrp(grp, b, xi, zi);
        df_vb = b * D3 + xi * TX * D2 + zi * ZSL + loff + yi * TY * D;
    };
    auto dfIssue = [&](f32x2& a, f32x2& b2, f32x2& c) {
        const float* p = ddf + (size_t)df_vb * 3;
        a  = __builtin_nontemporal_load((const f32x2*)p);
        b2 = __builtin_nontemporal_load((const f32x2*)(p + 2));
        c  = __builtin_nontemporal_load((const f32x2*)(p + 4));
    };
    auto dfAdv = [&]() {
        df_vb += TY * D;
        if (--df_yleft == 0) { dfInit(df_grp + 1, 0); }
    };

    // ---- compute cursor ----
    int cp_grp, cp_yleft, cp_vol, cp_xwb, cp_ywb, cp_zwb, cp_vb;
    float cp_xgf, cp_ygf, cp_zgf;
    auto cpInit = [&](int grp, int yi) {
        cp_grp = grp; cp_yleft = TPDY - yi;
        int b, xi, zi; decodeGrp(grp, b, xi, zi);
        cp_vol = b * D3;
        cp_xwb = xi * TX - HXL;
        cp_zwb = zi * ZSL - HZL;
        cp_ywb = yi * TY - HYL;
        cp_vb  = cp_vol + xi * TX * D2 + zi * ZSL + loff + yi * TY * D;
        cp_xgf = (float)(xi * TX + rx);
        cp_ygf = (float)(yi * TY + ry);
        cp_zgf = (float)(zi * ZSL + zbl);
    };
    auto cpAdv = [&]() {
        if (--cp_yleft == 0) { cpInit(cp_grp + 1, 0); }
        else { cp_ywb += TY; cp_ygf += (float)TY; cp_vb += TY * D; }
    };

    auto doIter = [&](int it, f32x2 q0, f32x2 q1, f32x2 q2,
                      f32x2& n0, f32x2& n1, f32x2& n2,
                      float* bufc, float* bufs) {
        const float maxf = (float)(D - 1);
        const float dxs[2] = {q0.x, q1.y};
        const float dys[2] = {q0.y, q2.x};
        const float dzs[2] = {q1.x, q2.y};
        float wxs[2], wys[2], wzs[2];
        int bases[2];
        unsigned flags = 0, shb = 0;
        f32x2 fb00[2] = {}, fb01[2] = {}, fb10[2] = {}, fb11[2] = {};
        const float* volC = image + cp_vol;

        // ---- phase A: coords, weights, rare fallback loads (issued EARLY) ----
#pragma unroll
        for (int j = 0; j < 2; ++j) {
            float fx = fminf(fmaxf(cp_xgf + dxs[j], 0.0f), maxf);
            float fy = fminf(fmaxf(cp_ygf + dys[j], 0.0f), maxf);
            float fz = fminf(fmaxf(cp_zgf + (float)j + dzs[j], 0.0f), maxf);
            int x0 = (int)fx, y0 = (int)fy, z0 = (int)fz;
            wxs[j] = fx - (float)x0;
            wys[j] = fy - (float)y0;
            wzs[j] = fz - (float)z0;
            int sx0 = x0 - cp_xwb, sy0 = y0 - cp_ywb, sz0 = z0 - cp_zwb;
            bool inWin = ((unsigned)sx0 <= (unsigned)(WINX - 2)) &
                         ((unsigned)sy0 <= (unsigned)(WINY - 2)) &
                         ((unsigned)sz0 <= (unsigned)(ZWIN - 2));
            flags |= (unsigned)inWin << j;
            int base = (sx0 * WINY + sy0) * ZWIN + sz0;
            bases[j] = (int)min((unsigned)base, (unsigned)BASEMAX);  // garbage-safe
            if (!inWin) {                    // rare: beyond halo -> exact path
                int x1 = min(x0 + 1, D - 1);
                int y1 = min(y0 + 1, D - 1);
                int zc = min(z0, D - 2);
                shb |= (unsigned)(z0 > zc) << j;    // z0==159 -> wz==0
                fb00[j] = *(const f32x2*)(volC + x0 * D2 + y0 * D + zc);
                fb01[j] = *(const f32x2*)(volC + x0 * D2 + y1 * D + zc);
                fb10[j] = *(const f32x2*)(volC + x1 * D2 + y0 * D + zc);
                fb11[j] = *(const f32x2*)(volC + x1 * D2 + y1 * D + zc);
            }
        }
        __builtin_amdgcn_sched_barrier(0);

        // ---- issue ddf(i+1) THEN stage(i+2) (order matters for vmcnt math) ----
        if (it + 1 < CNT) { dfIssue(n0, n1, n2); dfAdv(); }
        __builtin_amdgcn_sched_barrier(0);
        if (it + 2 < CNT) { sgIssue(bufs); sgAdv(); }
        __builtin_amdgcn_sched_barrier(0);

        // ---- phase B: LDS reads, fallback select, interpolate, store ----
        float res[2];
#pragma unroll
        for (int j = 0; j < 2; ++j) {
            int b00 = bases[j];
            float a0 = bufc[b00],                     a1 = bufc[b00 + 1];
            float c0 = bufc[b00 + ZWIN],              c1 = bufc[b00 + ZWIN + 1];
            float e0 = bufc[b00 + WINY * ZWIN],       e1 = bufc[b00 + WINY * ZWIN + 1];
            float g0 = bufc[b00 + (WINY + 1) * ZWIN], g1 = bufc[b00 + (WINY + 1) * ZWIN + 1];
            if (!((flags >> j) & 1)) {
                bool sh = (shb >> j) & 1;
                a0 = sh ? fb00[j].y : fb00[j].x;  a1 = fb00[j].y;
                c0 = sh ? fb01[j].y : fb01[j].x;  c1 = fb01[j].y;
                e0 = sh ? fb10[j].y : fb10[j].x;  e1 = fb10[j].y;
                g0 = sh ? fb11[j].y : fb11[j].x;  g1 = fb11[j].y;
            }
            float wx = wxs[j], wy = wys[j], wz = wzs[j];
            float ux = 1.0f - wx, uy = 1.0f - wy, uz = 1.0f - wz;
            res[j] = (a0 * uz + a1 * wz) * (ux * uy)
                   + (c0 * uz + c1 * wz) * (ux * wy)
                   + (e0 * uz + e1 * wz) * (wx * uy)
                   + (g0 * uz + g1 * wz) * (wx * wy);
        }
        f32x2 o = {res[0], res[1]};
        *(f32x2*)(out + cp_vb) = o;          // normal store (L2-merged lines)

        // ---- gate: only require stage(i+1)/ddf done; keep i+2 stage in flight ----
        __builtin_amdgcn_sched_barrier(0);
        if (it + 2 < CNT) {
            if (w < 3) { asm volatile("s_waitcnt vmcnt(7)" ::: "memory"); }
            else       { asm volatile("s_waitcnt vmcnt(6)" ::: "memory"); }
        } else {
            asm volatile("s_waitcnt vmcnt(1)" ::: "memory");
        }
        __builtin_amdgcn_sched_barrier(0);
        __builtin_amdgcn_s_barrier();
        __builtin_amdgcn_sched_barrier(0);
        cpAdv();
    };

    // ---- prologue: stage(0)->buf0, stage(1)->buf1, ddf(0) ----
    float* bC_ = lds;
    float* bR_ = lds + LDSPAD;
    float* bS_ = lds + 2 * LDSPAD;

    sgInit(grp0, yi0);
    dfInit(grp0, yi0);
    cpInit(grp0, yi0);

    sgIssue(bC_); sgAdv();
    sgIssue(bR_); sgAdv();
    f32x2 qA0, qA1, qA2, qB0, qB1, qB2;
    dfIssue(qA0, qA1, qA2); dfAdv();
    asm volatile("s_waitcnt vmcnt(3)" ::: "memory");   // both stages landed
    __builtin_amdgcn_sched_barrier(0);
    __builtin_amdgcn_s_barrier();
    __builtin_amdgcn_sched_barrier(0);

    int it = 0;
    for (;;) {
        doIter(it, qA0, qA1, qA2, qB0, qB1, qB2, bC_, bS_);
        { float* t = bC_; bC_ = bR_; bR_ = bS_; bS_ = t; }
        if (++it == CNT) break;
        doIter(it, qB0, qB1, qB2, qA0, qA1, qA2, bC_, bS_);
        { float* t = bC_; bC_ = bR_; bR_ = bS_; bS_ = t; }
        if (++it == CNT) break;
    }
}

extern "C" void kernel_launch(void* const* d_in, const int* in_sizes, int n_in,
                              void* d_out, int out_size, void* d_ws, size_t ws_size,
                              hipStream_t stream) {
    const float* ddf   = (const float*)d_in[0];
    const float* image = (const float*)d_in[1];
    float* out = (float*)d_out;

    hipFuncSetAttribute((const void*)warp_kernel,
                        hipFuncAttributeMaxDynamicSharedMemorySize,
                        3 * LDSPAD * (int)sizeof(float));

    warp_kernel<<<NBLK, TPB, 3 * LDSPAD * sizeof(float), stream>>>(ddf, image, out);
}

// Round 11
// 95.672 us; speedup vs baseline: 1.5263x; 1.4648x over previous
//
#include <hip/hip_runtime.h>

#define D     160
#define D2    (D * D)
#define D3    (D * D * D)
#define NB    4
#define TL    4                     // xy tile edge
#define ZSL   80                    // z slab
#define ZWIN  88                    // z slots [zl-4 .. zl+83]
#define WINX  11                    // x slots [xt-3 .. xt+7]
#define RING  18                    // y-plane ring (>= read 10 + 2*4 depth)
#define PLANE 1024                  // padded plane floats (11*88=968 -> 1024)
#define LDSF  (RING * PLANE)        // 18432 floats = 72 KB -> 2 WG/CU
#define TPB   640
#define TPD   (D / TL)              // 40
#define NZS   (D / ZSL)             // 2
#define CNT   10                    // y-tiles per block
#define NRUN  (TPD / CNT)           // 4 y-runs per (b,xi,zs) group
#define NGRP  (NB * TPD * NZS)      // 320
#define NBLK  (NGRP * NRUN)         // 1280 = exactly 5 blocks/CU

typedef float f32x2 __attribute__((ext_vector_type(2)));

__global__ __launch_bounds__(TPB) void warp_kernel(
    const float* __restrict__ ddf,     // [B, D, D, D, 3]
    const float* __restrict__ image,   // [B, D, D, D]
    float* __restrict__ out)           // [B, D, D, D]
{
    extern __shared__ float buf[];     // RING * PLANE floats

    const int tid  = threadIdx.x;
    const int w    = tid >> 6;
    const int lane = tid & 63;
    const int row  = tid / 40;             // 0..15
    const int zch  = tid - row * 40;       // 0..39
    const int rx   = row >> 2, ry = row & 3, zbl = zch * 2;

    // ---- block decode (XCD-chunked; 1280 % 8 == 0 -> bijective) ----
    int g    = blockIdx.x;
    int gx8  = (g & 7) * (NBLK / 8) + (g >> 3);
    int yrun = gx8 & 3;
    int t    = gx8 >> 2;
    int zs   = t & 1; t >>= 1;
    int xi   = t % TPD;
    int b    = t / TPD;

    const int yt0    = yrun * (CNT * TL);  // 0,40,80,120 (no group straddle)
    const int xt     = xi * TL, zl = zs * ZSL;
    const int xwb    = xt - 3,  zwb = zl - 4;
    const int volofs = b * D3;
    const float* vol = image + volofs;

    // ---- per-lane stage constants for k = 0..3 (block-fixed x/z source) ----
    int pfix[4];
#pragma unroll
    for (int k = 0; k < 4; ++k) {
        int f  = k * 256 + lane * 4;       // multiple of 4 -> 16B aligned
        int sx = f / ZWIN;                 // 0..11 (>=11 lands in pad, harmless)
        int zo = f - sx * ZWIN;
        int srcx = min(max(xwb + sx, 0), D - 1);
        int srcz = min(max(zwb + zo, 0), D - 4);
        pfix[k] = volofs + srcx * D2 + srcz;
    }

    // ring slot trackers (wave-uniform scalars)
    int su = (yt0 + 33) % RING;            // slot of plane ywb = yt-3
    int ps = su + 14; if (ps >= RING) ps -= RING;   // slot of plane yt+11

    // voxel cursor
    int   vb  = volofs + (xt + rx) * D2 + (yt0 + ry) * D + (zl + zbl);
    float ygf = (float)(yt0 + ry);
    const float xgf = (float)(xt + rx);
    const float zgf = (float)(zl + zbl);
    int   ywb = yt0 - 3;

    // ---- prologue: stage 14 planes [yt0-3 .. yt0+10], ddf(0), full drain ----
    for (int m = 0;; ++m) {
        int L = w + m * 10;
        if (L >= 56) break;
        int pi = L >> 2, k = L & 3;
        int p  = yt0 - 3 + pi;
        int srcy = min(max(p, 0), D - 1);
        int slot = (p + 36) % RING;
        const float* gp = image + pfix[k] + srcy * D;
        __builtin_amdgcn_global_load_lds(
            (const __attribute__((address_space(1))) void*)gp,
            (__attribute__((address_space(3))) void*)(buf + slot * PLANE + k * 256),
            16, 0, 0);
    }
    f32x2 q0, q1, q2, n0 = {0, 0}, n1 = {0, 0}, n2 = {0, 0};
    {
        const float* p = ddf + (size_t)vb * 3;
        q0 = __builtin_nontemporal_load((const f32x2*)p);
        q1 = __builtin_nontemporal_load((const f32x2*)(p + 2));
        q2 = __builtin_nontemporal_load((const f32x2*)(p + 4));
    }
    asm volatile("s_waitcnt vmcnt(0)" ::: "memory");
    __builtin_amdgcn_sched_barrier(0);
    __builtin_amdgcn_s_barrier();
    __builtin_amdgcn_sched_barrier(0);

#pragma unroll 1
    for (int it = 0; it < CNT; ++it) {
        const float maxf = (float)(D - 1);
        // ---- phase A: coords, weights, ring bases, rare fallback loads ----
        const float dxs[2] = {q0.x, q1.y};
        const float dys[2] = {q0.y, q2.x};
        const float dzs[2] = {q1.x, q2.y};
        float wxs[2], wys[2], wzs[2];
        int ba[2], bc[2];
        unsigned flags = 0, shb = 0;
        f32x2 fb00[2] = {}, fb01[2] = {}, fb10[2] = {}, fb11[2] = {};
#pragma unroll
        for (int j = 0; j < 2; ++j) {
            float fx = fminf(fmaxf(xgf + dxs[j], 0.0f), maxf);
            float fy = fminf(fmaxf(ygf + dys[j], 0.0f), maxf);
            float fz = fminf(fmaxf(zgf + (float)j + dzs[j], 0.0f), maxf);
            int x0 = (int)fx, y0 = (int)fy, z0 = (int)fz;
            wxs[j] = fx - (float)x0;
            wys[j] = fy - (float)y0;
            wzs[j] = fz - (float)z0;
            int sx0 = x0 - xwb, sy0 = y0 - ywb, sz0 = z0 - zwb;
            bool inWin = ((unsigned)sx0 <= 9u) & ((unsigned)sy0 <= 8u) &
                         ((unsigned)sz0 <= 86u);
            flags |= (unsigned)inWin << j;
            int csx = (int)min((unsigned)sx0 & 15u, 9u);     // garbage-safe clamps
            int csy = (int)min((unsigned)sy0 & 15u, 8u);
            int csz = (int)min((unsigned)sz0 & 127u, 86u);
            int t0 = su + csy; if (t0 >= RING) t0 -= RING;   // ring slot of y0
            int t1 = t0 + 1;   if (t1 >= RING) t1 = 0;       // slot of y0+1
            ba[j] = t0 * PLANE + csx * ZWIN + csz;
            bc[j] = t1 * PLANE + csx * ZWIN + csz;
            if (!inWin) {                   // rare: beyond window -> exact path
                int x1 = min(x0 + 1, D - 1);
                int y1 = min(y0 + 1, D - 1);
                int zc = min(z0, D - 2);
                shb |= (unsigned)(z0 > zc) << j;    // z0==159 -> wz==0
                fb00[j] = *(const f32x2*)(vol + x0 * D2 + y0 * D + zc);
                fb01[j] = *(const f32x2*)(vol + x0 * D2 + y1 * D + zc);
                fb10[j] = *(const f32x2*)(vol + x1 * D2 + y0 * D + zc);
                fb11[j] = *(const f32x2*)(vol + x1 * D2 + y1 * D + zc);
            }
        }
        __builtin_amdgcn_sched_barrier(0);

        // ---- issue ddf(i+1) + stage B(i+2): 4 new y-planes, 16 loads total ----
        if (it + 1 < CNT) {
            const float* p = ddf + (size_t)(vb + TL * D) * 3;
            n0 = __builtin_nontemporal_load((const f32x2*)p);
            n1 = __builtin_nontemporal_load((const f32x2*)(p + 2));
            n2 = __builtin_nontemporal_load((const f32x2*)(p + 4));
        }
        const bool staged = (it + 2 < CNT);
        if (staged) {
            int ptop = ywb + 14;            // first new plane = yt + 11
            {
                int pi = w >> 2, k = w & 3;
                int p = ptop + pi;
                int srcy = min(p, D - 1);
                int slot = ps + pi; if (slot >= RING) slot -= RING;
                const float* gp = image + pfix[k] + srcy * D;
                __builtin_amdgcn_global_load_lds(
                    (const __attribute__((address_space(1))) void*)gp,
                    (__attribute__((address_space(3))) void*)(buf + slot * PLANE + k * 256),
                    16, 0, 0);
            }
            if (w < 6) {
                int L = w + 10;
                int pi = L >> 2, k = L & 3;
                int p = ptop + pi;
                int srcy = min(p, D - 1);
                int slot = ps + pi; if (slot >= RING) slot -= RING;
                const float* gp = image + pfix[k] + srcy * D;
                __builtin_amdgcn_global_load_lds(
                    (const __attribute__((address_space(1))) void*)gp,
                    (__attribute__((address_space(3))) void*)(buf + slot * PLANE + k * 256),
                    16, 0, 0);
            }
        }
        __builtin_amdgcn_sched_barrier(0);

        // ---- phase B: LDS reads, fallback select, interpolate, store ----
        float res[2];
#pragma unroll
        for (int j = 0; j < 2; ++j) {
            float a0 = buf[ba[j]],          a1 = buf[ba[j] + 1];
            float c0 = buf[bc[j]],          c1 = buf[bc[j] + 1];
            float e0 = buf[ba[j] + ZWIN],   e1 = buf[ba[j] + ZWIN + 1];
            float g0 = buf[bc[j] + ZWIN],   g1 = buf[bc[j] + ZWIN + 1];
            if (!((flags >> j) & 1)) {
                bool sh = (shb >> j) & 1;
                a0 = sh ? fb00[j].y : fb00[j].x;  a1 = fb00[j].y;
                c0 = sh ? fb01[j].y : fb01[j].x;  c1 = fb01[j].y;
                e0 = sh ? fb10[j].y : fb10[j].x;  e1 = fb10[j].y;
                g0 = sh ? fb11[j].y : fb11[j].x;  g1 = fb11[j].y;
            }
            float wx = wxs[j], wy = wys[j], wz = wzs[j];
            float ux = 1.0f - wx, uy = 1.0f - wy, uz = 1.0f - wz;
            res[j] = (a0 * uz + a1 * wz) * (ux * uy)
                   + (c0 * uz + c1 * wz) * (ux * wy)
                   + (e0 * uz + e1 * wz) * (wx * uy)
                   + (g0 * uz + g1 * wz) * (wx * wy);
        }
        f32x2 o = {res[0], res[1]};
        __builtin_nontemporal_store(o, (f32x2*)(out + vb));
        __builtin_amdgcn_sched_barrier(0);

        // ---- gate: require B(i+1) retired; allow store+ddf+B(i+2) in flight ----
        if (staged) {
            if (w < 6) { asm volatile("s_waitcnt vmcnt(6)" ::: "memory"); }
            else       { asm volatile("s_waitcnt vmcnt(5)" ::: "memory"); }
        } else {
            asm volatile("s_waitcnt vmcnt(4)" ::: "memory");
        }
        __builtin_amdgcn_sched_barrier(0);
        __builtin_amdgcn_s_barrier();
        __builtin_amdgcn_sched_barrier(0);

        // ---- advance cursors ----
        q0 = n0; q1 = n1; q2 = n2;
        vb += TL * D; ygf += (float)TL; ywb += TL;
        su += TL; if (su >= RING) su -= RING;
        ps += TL; if (ps >= RING) ps -= RING;
    }
}

extern "C" void kernel_launch(void* const* d_in, const int* in_sizes, int n_in,
                              void* d_out, int out_size, void* d_ws, size_t ws_size,
                              hipStream_t stream) {
    const float* ddf   = (const float*)d_in[0];
    const float* image = (const float*)d_in[1];
    float* out = (float*)d_out;

    hipFuncSetAttribute((const void*)warp_kernel,
                        hipFuncAttributeMaxDynamicSharedMemorySize,
                        LDSF * (int)sizeof(float));

    warp_kernel<<<NBLK, TPB, LDSF * sizeof(float), stream>>>(ddf, image, out);
}

// Round 12
// 93.129 us; speedup vs baseline: 1.5680x; 1.0273x over previous
//
#include <hip/hip_runtime.h>

#define D     160
#define D2    (D * D)
#define D3    (D * D * D)
#define NB    4
#define TL    4                     // xy tile edge
#define ZSL   80                    // z slab
#define ZWIN  88                    // z slots [zl-4 .. zl+83]
#define WINX  11                    // x slots [xt-3 .. xt+7]
#define RING  18                    // y-plane ring (read 10 + 2*4 depth)
#define PLANE 1024                  // padded plane floats (11*88=968 -> 1024)
#define LDSF  (RING * PLANE)        // 18432 floats = 72 KB -> 2 WG/CU
#define TPB   640
#define TPD   (D / TL)              // 40
#define NZS   (D / ZSL)             // 2
#define CNT   10                    // y-tiles per block
#define NRUN  (TPD / CNT)           // 4
#define NGRP  (NB * TPD * NZS)      // 320
#define NBLK  (NGRP * NRUN)         // 1280 = exactly 5 blocks/CU

typedef float f32x2 __attribute__((ext_vector_type(2)));
typedef int   i32x2 __attribute__((ext_vector_type(2)));

__global__ __launch_bounds__(TPB) void warp_kernel(
    const float* __restrict__ ddf,     // [B, D, D, D, 3]
    const float* __restrict__ image,   // [B, D, D, D]
    float* __restrict__ out)           // [B, D, D, D]
{
    extern __shared__ float buf[];     // RING * PLANE floats

    const int tid  = threadIdx.x;
    const int w    = tid >> 6;
    const int lane = tid & 63;
    const int row  = tid / 40;             // 0..15
    const int zch  = tid - row * 40;       // 0..39
    const int rx   = row >> 2, ry = row & 3, zbl = zch * 2;

    // ---- block decode (XCD-chunked; 1280 % 8 == 0 -> bijective) ----
    int g    = blockIdx.x;
    int gx8  = (g & 7) * (NBLK / 8) + (g >> 3);
    int yrun = gx8 & 3;
    int t    = gx8 >> 2;
    int zs   = t & 1; t >>= 1;
    int xi   = t % TPD;
    int b    = t / TPD;

    const int yt0    = yrun * (CNT * TL);  // 0,40,80,120
    const int xt     = xi * TL, zl = zs * ZSL;
    const int xwb    = xt - 3,  zwb = zl - 4;
    const int volofs = b * D3;
    const float* vol = image + volofs;

    // ---- per-lane stage constants for k = 0..3 (block-fixed x/z source) ----
    int pfix[4];
#pragma unroll
    for (int k = 0; k < 4; ++k) {
        int f  = k * 256 + lane * 4;       // multiple of 4 -> 16B aligned
        int sx = f / ZWIN;                 // 0..11 (>=11 lands in pad, harmless)
        int zo = f - sx * ZWIN;
        int srcx = min(max(xwb + sx, 0), D - 1);
        int srcz = min(max(zwb + zo, 0), D - 4);
        pfix[k] = volofs + srcx * D2 + srcz;
    }

    // ring slot trackers (wave-uniform)
    int su = (yt0 + 33) % RING;            // slot of plane ywb = yt-3
    int ps = su + 14; if (ps >= RING) ps -= RING;   // slot of plane yt+11

    // voxel cursor
    int   vb  = volofs + (xt + rx) * D2 + (yt0 + ry) * D + (zl + zbl);
    float ygf = (float)(yt0 + ry);
    const float xgf = (float)(xt + rx);
    const float zgf = (float)(zl + zbl);
    int   ywb = yt0 - 3;

    const f32x2 zero2 = {0.0f, 0.0f};
    const f32x2 one2  = {1.0f, 1.0f};
    const f32x2 max2  = {(float)(D - 1), (float)(D - 1)};

    // ---- prologue: stage 14 planes [yt0-3 .. yt0+10], ddf(0), full drain ----
    for (int m = 0;; ++m) {
        int L = w + m * 10;
        if (L >= 56) break;
        int pi = L >> 2, k = L & 3;
        int p  = yt0 - 3 + pi;
        int srcy = min(max(p, 0), D - 1);
        int slot = (p + 36) % RING;
        const float* gp = image + pfix[k] + srcy * D;
        __builtin_amdgcn_global_load_lds(
            (const __attribute__((address_space(1))) void*)gp,
            (__attribute__((address_space(3))) void*)(buf + slot * PLANE + k * 256),
            16, 0, 0);
    }
    f32x2 q0, q1, q2, n0 = {0, 0}, n1 = {0, 0}, n2 = {0, 0};
    {
        const float* p = ddf + (size_t)vb * 3;
        q0 = __builtin_nontemporal_load((const f32x2*)p);
        q1 = __builtin_nontemporal_load((const f32x2*)(p + 2));
        q2 = __builtin_nontemporal_load((const f32x2*)(p + 4));
    }
    asm volatile("s_waitcnt vmcnt(0)" ::: "memory");
    __builtin_amdgcn_sched_barrier(0);
    __builtin_amdgcn_s_barrier();
    __builtin_amdgcn_sched_barrier(0);

#pragma unroll 1
    for (int it = 0; it < CNT; ++it) {
        // ---- phase A (packed over j): coords, weights, ring bases ----
        f32x2 dx = {q0.x, q1.y};
        f32x2 dy = {q0.y, q2.x};
        f32x2 dz = {q1.x, q2.y};
        f32x2 xg2 = {xgf, xgf};
        f32x2 yg2 = {ygf, ygf};
        f32x2 zg2 = {zgf, zgf + 1.0f};

        f32x2 fx2 = __builtin_elementwise_min(
                        __builtin_elementwise_max(xg2 + dx, zero2), max2);
        f32x2 fy2 = __builtin_elementwise_min(
                        __builtin_elementwise_max(yg2 + dy, zero2), max2);
        f32x2 fz2 = __builtin_elementwise_min(
                        __builtin_elementwise_max(zg2 + dz, zero2), max2);

        i32x2 X0 = __builtin_convertvector(fx2, i32x2);   // trunc == floor (>=0)
        i32x2 Y0 = __builtin_convertvector(fy2, i32x2);
        i32x2 Z0 = __builtin_convertvector(fz2, i32x2);
        f32x2 wx2 = fx2 - __builtin_convertvector(X0, f32x2);
        f32x2 wy2 = fy2 - __builtin_convertvector(Y0, f32x2);
        f32x2 wz2 = fz2 - __builtin_convertvector(Z0, f32x2);

        int ba[2], bc[2];
        unsigned flags = 0, shb = 0;
        f32x2 fb00[2] = {}, fb01[2] = {}, fb10[2] = {}, fb11[2] = {};
#pragma unroll
        for (int j = 0; j < 2; ++j) {
            int x0 = X0[j], y0 = Y0[j], z0 = Z0[j];
            int sx0 = x0 - xwb, sy0 = y0 - ywb, sz0 = z0 - zwb;
            bool inWin = ((unsigned)sx0 <= 9u) & ((unsigned)sy0 <= 8u) &
                         ((unsigned)sz0 <= 86u);
            flags |= (unsigned)inWin << j;
            int csx = min(max(sx0, 0), 9);    // v_med3_i32, garbage-safe
            int csy = min(max(sy0, 0), 8);
            int csz = min(max(sz0, 0), 86);
            int t0 = su + csy; if (t0 >= RING) t0 -= RING;   // slot of y0
            int t1 = t0 + 1;   if (t1 >= RING) t1 = 0;       // slot of y0+1
            ba[j] = t0 * PLANE + csx * ZWIN + csz;
            bc[j] = t1 * PLANE + csx * ZWIN + csz;
            if (!inWin) {                   // rare: beyond window -> exact path
                int x1 = min(x0 + 1, D - 1);
                int y1 = min(y0 + 1, D - 1);
                int zc = min(z0, D - 2);
                shb |= (unsigned)(z0 > zc) << j;    // z0==159 -> wz==0
                fb00[j] = *(const f32x2*)(vol + x0 * D2 + y0 * D + zc);
                fb01[j] = *(const f32x2*)(vol + x0 * D2 + y1 * D + zc);
                fb10[j] = *(const f32x2*)(vol + x1 * D2 + y0 * D + zc);
                fb11[j] = *(const f32x2*)(vol + x1 * D2 + y1 * D + zc);
            }
        }
        __builtin_amdgcn_sched_barrier(0);

        // ---- issue ddf(i+1) + stage(i+2): 4 new y-planes, 16 loads total ----
        if (it + 1 < CNT) {
            const float* p = ddf + (size_t)(vb + TL * D) * 3;
            n0 = __builtin_nontemporal_load((const f32x2*)p);
            n1 = __builtin_nontemporal_load((const f32x2*)(p + 2));
            n2 = __builtin_nontemporal_load((const f32x2*)(p + 4));
        }
        const bool staged = (it + 2 < CNT);
        if (staged) {
            int ptop = ywb + 14;            // first new plane = yt + 11
            {
                int pi = w >> 2, k = w & 3;
                int p = ptop + pi;
                int srcy = min(p, D - 1);
                int slot = ps + pi; if (slot >= RING) slot -= RING;
                const float* gp = image + pfix[k] + srcy * D;
                __builtin_amdgcn_global_load_lds(
                    (const __attribute__((address_space(1))) void*)gp,
                    (__attribute__((address_space(3))) void*)(buf + slot * PLANE + k * 256),
                    16, 0, 0);
            }
            if (w < 6) {
                int L = w + 10;
                int pi = L >> 2, k = L & 3;
                int p = ptop + pi;
                int srcy = min(p, D - 1);
                int slot = ps + pi; if (slot >= RING) slot -= RING;
                const float* gp = image + pfix[k] + srcy * D;
                __builtin_amdgcn_global_load_lds(
                    (const __attribute__((address_space(1))) void*)gp,
                    (__attribute__((address_space(3))) void*)(buf + slot * PLANE + k * 256),
                    16, 0, 0);
            }
        }
        __builtin_amdgcn_sched_barrier(0);

        // ---- phase B: LDS gathers (scalar), packed interpolation ----
        float a0s[2], a1s[2], c0s[2], c1s[2], e0s[2], e1s[2], g0s[2], g1s[2];
#pragma unroll
        for (int j = 0; j < 2; ++j) {
            a0s[j] = buf[ba[j]];          a1s[j] = buf[ba[j] + 1];
            c0s[j] = buf[bc[j]];          c1s[j] = buf[bc[j] + 1];
            e0s[j] = buf[ba[j] + ZWIN];   e1s[j] = buf[ba[j] + ZWIN + 1];
            g0s[j] = buf[bc[j] + ZWIN];   g1s[j] = buf[bc[j] + ZWIN + 1];
            if (!((flags >> j) & 1)) {
                bool sh = (shb >> j) & 1;
                a0s[j] = sh ? fb00[j].y : fb00[j].x;  a1s[j] = fb00[j].y;
                c0s[j] = sh ? fb01[j].y : fb01[j].x;  c1s[j] = fb01[j].y;
                e0s[j] = sh ? fb10[j].y : fb10[j].x;  e1s[j] = fb10[j].y;
                g0s[j] = sh ? fb11[j].y : fb11[j].x;  g1s[j] = fb11[j].y;
            }
        }
        f32x2 A0 = {a0s[0], a0s[1]}, A1 = {a1s[0], a1s[1]};
        f32x2 C0 = {c0s[0], c0s[1]}, C1 = {c1s[0], c1s[1]};
        f32x2 E0 = {e0s[0], e0s[1]}, E1 = {e1s[0], e1s[1]};
        f32x2 G0 = {g0s[0], g0s[1]}, G1 = {g1s[0], g1s[1]};

        f32x2 ux2 = one2 - wx2, uy2 = one2 - wy2, uz2 = one2 - wz2;
        f32x2 r2 = (A0 * uz2 + A1 * wz2) * (ux2 * uy2)
                 + (C0 * uz2 + C1 * wz2) * (ux2 * wy2)
                 + (E0 * uz2 + E1 * wz2) * (wx2 * uy2)
                 + (G0 * uz2 + G1 * wz2) * (wx2 * wy2);
        __builtin_nontemporal_store(r2, (f32x2*)(out + vb));
        __builtin_amdgcn_sched_barrier(0);

        // ---- gate: require stage(i+1) retired; allow store+ddf+stage(i+2) ----
        if (staged) {
            if (w < 6) { asm volatile("s_waitcnt vmcnt(6)" ::: "memory"); }
            else       { asm volatile("s_waitcnt vmcnt(5)" ::: "memory"); }
        } else {
            asm volatile("s_waitcnt vmcnt(4)" ::: "memory");
        }
        __builtin_amdgcn_sched_barrier(0);
        __builtin_amdgcn_s_barrier();
        __builtin_amdgcn_sched_barrier(0);

        // ---- advance cursors ----
        q0 = n0; q1 = n1; q2 = n2;
        vb += TL * D; ygf += (float)TL; ywb += TL;
        su += TL; if (su >= RING) su -= RING;
        ps += TL; if (ps >= RING) ps -= RING;
    }
}

extern "C" void kernel_launch(void* const* d_in, const int* in_sizes, int n_in,
                              void* d_out, int out_size, void* d_ws, size_t ws_size,
                              hipStream_t stream) {
    const float* ddf   = (const float*)d_in[0];
    const float* image = (const float*)d_in[1];
    float* out = (float*)d_out;

    hipFuncSetAttribute((const void*)warp_kernel,
                        hipFuncAttributeMaxDynamicSharedMemorySize,
                        LDSF * (int)sizeof(float));

    warp_kernel<<<NBLK, TPB, LDSF * sizeof(float), stream>>>(ddf, image, out);
}